// Round 1
// baseline (344.068 us; speedup 1.0000x reference)
//
#include <hip/hip_runtime.h>
#include <math.h>

#define B_ 8
#define T_ 1000
#define C_ 8
#define F_ 257
#define A_ 320

// ---------------- Kernel 1: (B,T,C,F) -> (B,F,C,T) interleaved float2 ----------
__global__ __launch_bounds__(256) void k_transpose(
    const float* __restrict__ dre, const float* __restrict__ dim_,
    float2* __restrict__ xt) {
  __shared__ float2 tile[32][33];
  int bc = blockIdx.z;
  int b = bc >> 3, c = bc & 7;
  int t0 = blockIdx.y * 32, f0 = blockIdx.x * 32;
  int tx = threadIdx.x, ty = threadIdx.y;
#pragma unroll
  for (int j = 0; j < 4; ++j) {
    int t = t0 + ty + j * 8, f = f0 + tx;
    if (t < T_ && f < F_) {
      size_t idx = ((size_t)(b * T_ + t) * C_ + c) * F_ + f;
      tile[ty + j * 8][tx] = make_float2(dre[idx], dim_[idx]);
    }
  }
  __syncthreads();
#pragma unroll
  for (int j = 0; j < 4; ++j) {
    int f = f0 + ty + j * 8, t = t0 + tx;
    if (t < T_ && f < F_) {
      xt[((size_t)(b * F_ + f) * C_ + c) * T_ + t] = tile[tx][ty + j * 8];
    }
  }
}

// ---------------- Kernel 2: PSDs (both masks, one pass) + attention features ----
__global__ __launch_bounds__(256) void k_psd(
    const float2* __restrict__ xt,
    const float* __restrict__ ms, const float* __restrict__ mn,
    float2* __restrict__ psd_s, float2* __restrict__ psd_n,
    float* __restrict__ feat) {
  __shared__ float2 xl[C_][T_];   // 64 KB
  int bf = blockIdx.x;            // b*F + f
  int b = bf / F_;
  int f = bf - b * F_;
  int tid = threadIdx.x;

  // stage x[b,f,:,:] into LDS (coalesced float2)
  const float2* xg = xt + (size_t)bf * (C_ * T_);
  float2* xflat = &xl[0][0];
  for (int i = tid; i < C_ * T_; i += 256) xflat[i] = xg[i];
  __syncthreads();

  int g = tid >> 5;       // channel c owned by this 32-lane group
  int lane = tid & 31;
  const float* msg = ms + (size_t)bf * (C_ * T_) + g * T_;
  const float* mng = mn + (size_t)bf * (C_ * T_) + g * T_;

  float2 as_[C_], an_[C_];
#pragma unroll
  for (int e = 0; e < C_; ++e) { as_[e] = make_float2(0.f, 0.f); an_[e] = make_float2(0.f, 0.f); }
  float ss = 0.f, sn = 0.f;

  for (int t = lane; t < T_; t += 32) {
    float vms = msg[t], vmn = mng[t];
    ss += vms; sn += vmn;
    float2 xc = xl[g][t];
#pragma unroll
    for (int e = 0; e < C_; ++e) {
      float2 xe = xl[e][t];
      float tre = xc.x * xe.x + xc.y * xe.y;   // xc * conj(xe) .re
      float tim = xc.y * xe.x - xc.x * xe.y;   // .im
      as_[e].x += vms * tre; as_[e].y += vms * tim;
      an_[e].x += vmn * tre; an_[e].y += vmn * tim;
    }
  }

  // reduce across 32 lanes of the group (xor masks < 32 stay in-group)
#pragma unroll
  for (int s = 16; s >= 1; s >>= 1) {
    ss += __shfl_xor(ss, s);
    sn += __shfl_xor(sn, s);
#pragma unroll
    for (int e = 0; e < C_; ++e) {
      as_[e].x += __shfl_xor(as_[e].x, s);
      as_[e].y += __shfl_xor(as_[e].y, s);
      an_[e].x += __shfl_xor(an_[e].x, s);
      an_[e].y += __shfl_xor(an_[e].y, s);
    }
  }

  if (lane == 0) {
    float inv_s = 1.f / (ss + 1e-6f);
    float inv_n = 1.f / (sn + 1e-6f);
    float2* ps = psd_s + (size_t)bf * (C_ * C_) + g * C_;
    float2* pn = psd_n + (size_t)bf * (C_ * C_) + g * C_;
    float sr = 0.f, si = 0.f;
#pragma unroll
    for (int e = 0; e < C_; ++e) {
      float2 vs = make_float2(as_[e].x * inv_s, as_[e].y * inv_s);
      float2 vn = make_float2(an_[e].x * inv_n, an_[e].y * inv_n);
      ps[e] = vs; pn[e] = vn;
      if (e != g) { sr += vs.x; si += vs.y; }
    }
    sr *= (1.f / 7.f); si *= (1.f / 7.f);
    feat[(b * C_ + g) * F_ + f] = sqrtf(sr * sr + si * si);
  }
}

// ---------------- Kernel 3: attention MLP + softmax -> u (B,C) ------------------
__global__ __launch_bounds__(256) void k_attn(
    const float* __restrict__ feat, const float* __restrict__ wmlp,
    const float* __restrict__ bmlp, const float* __restrict__ wgv,
    const float* __restrict__ bgv, float* __restrict__ u) {
  __shared__ float fl[C_][F_];
  __shared__ float sred[4][C_];
  int b = blockIdx.x;
  int tid = threadIdx.x;
  float* flf = &fl[0][0];
  for (int i = tid; i < C_ * F_; i += 256) flf[i] = feat[b * C_ * F_ + i];
  __syncthreads();

  float ec[C_];
#pragma unroll
  for (int c = 0; c < C_; ++c) ec[c] = 0.f;

  for (int a = tid; a < A_; a += 256) {
    const float* wr = wmlp + a * F_;
    float acc[C_];
#pragma unroll
    for (int c = 0; c < C_; ++c) acc[c] = 0.f;
    for (int k = 0; k < F_; ++k) {
      float w = wr[k];
#pragma unroll
      for (int c = 0; c < C_; ++c) acc[c] += w * fl[c][k];
    }
    float bm = bmlp[a], wg = wgv[a];
#pragma unroll
    for (int c = 0; c < C_; ++c) ec[c] += wg * tanhf(acc[c] + bm);
  }

  // wave reduce (64-wide), then cross-wave via LDS
#pragma unroll
  for (int s = 32; s >= 1; s >>= 1) {
#pragma unroll
    for (int c = 0; c < C_; ++c) ec[c] += __shfl_xor(ec[c], s);
  }
  int wv = tid >> 6;
  if ((tid & 63) == 0) {
#pragma unroll
    for (int c = 0; c < C_; ++c) sred[wv][c] = ec[c];
  }
  __syncthreads();
  if (tid == 0) {
    float e[C_];
    float bg = bgv[0];
    float m = -1e30f;
#pragma unroll
    for (int c = 0; c < C_; ++c) {
      e[c] = 2.0f * (sred[0][c] + sred[1][c] + sred[2][c] + sred[3][c] + bg);
      m = fmaxf(m, e[c]);
    }
    float s = 0.f;
#pragma unroll
    for (int c = 0; c < C_; ++c) { e[c] = expf(e[c] - m); s += e[c]; }
    float inv = 1.f / s;
#pragma unroll
    for (int c = 0; c < C_; ++c) u[b * C_ + c] = e[c] * inv;
  }
}

// ---------------- Kernel 4: tik-reg + 8x8 complex solve + ws vector -------------
__global__ __launch_bounds__(64) void k_solve(
    const float2* __restrict__ psd_s, const float2* __restrict__ psd_n,
    const float* __restrict__ u, float2* __restrict__ wsv) {
  int bf = blockIdx.x;
  int b = bf / F_;
  int l = threadIdx.x;
  int r = l >> 3, q = l & 7;

  float2 M = psd_n[(size_t)bf * 64 + l];
  float2 R = psd_s[(size_t)bf * 64 + l];

  // trace(psd_n).real
  float td = (r == q) ? M.x : 0.f;
#pragma unroll
  for (int s = 32; s >= 1; s >>= 1) td += __shfl_xor(td, s);
  if (r == q) M.x += 1e-7f * (td * 0.125f) + 1e-8f;

  // Gauss-Jordan: M X = R  ->  R becomes X
#pragma unroll
  for (int k = 0; k < 8; ++k) {
    float pr = __shfl(M.x, k * 9), pi = __shfl(M.y, k * 9);
    float den = pr * pr + pi * pi;
    float ir = pr / den, ii = -pi / den;          // 1/pivot
    float mkr = __shfl(M.x, k * 8 + q), mki = __shfl(M.y, k * 8 + q);
    float rkr = __shfl(R.x, k * 8 + q), rki = __shfl(R.y, k * 8 + q);
    float gr = __shfl(M.x, r * 8 + k), gi = __shfl(M.y, r * 8 + k);
    if (r == k) {
      float nmr = M.x * ir - M.y * ii, nmi = M.x * ii + M.y * ir;
      float nrr = R.x * ir - R.y * ii, nri = R.x * ii + R.y * ir;
      M = make_float2(nmr, nmi); R = make_float2(nrr, nri);
    } else {
      float fr = gr * ir - gi * ii, fi = gr * ii + gi * ir;   // M[r,k]/pivot
      M.x -= fr * mkr - fi * mki; M.y -= fr * mki + fi * mkr;
      R.x -= fr * rkr - fi * rki; R.y -= fr * rki + fi * rkr;
    }
  }

  // trace(X), normalize, apply u
  float trr = (r == q) ? R.x : 0.f, tri = (r == q) ? R.y : 0.f;
#pragma unroll
  for (int s = 32; s >= 1; s >>= 1) { trr += __shfl_xor(trr, s); tri += __shfl_xor(tri, s); }
  trr += 1e-6f;  // + EPS (real)
  float den = trr * trr + tri * tri;
  float ir = trr / den, ii = -tri / den;
  float wr_ = R.x * ir - R.y * ii;   // ws_mat[r][q]
  float wi_ = R.x * ii + R.y * ir;
  float uq = u[b * C_ + q];
  float vr = wr_ * uq, vi = wi_ * uq;
#pragma unroll
  for (int s = 4; s >= 1; s >>= 1) { vr += __shfl_xor(vr, s); vi += __shfl_xor(vi, s); }
  if (q == 0) wsv[(size_t)bf * C_ + r] = make_float2(vr, vi);
}

// ---------------- Kernel 5: enhanced[b,t,f] = sum_c conj(ws) * x ----------------
__global__ __launch_bounds__(256) void k_bf(
    const float* __restrict__ dre, const float* __restrict__ dim_,
    const float2* __restrict__ wsv, float2* __restrict__ out) {
  __shared__ float2 wl[C_][F_];
  int blk = blockIdx.x;
  int b = blk / 125;
  int t0 = (blk - b * 125) * 8;
  int tid = threadIdx.x;
  // wsv layout [b][f][c] -> wl[c][f]
  for (int i = tid; i < C_ * F_; i += 256) {
    int f = i >> 3, c = i & 7;
    wl[c][f] = wsv[(size_t)b * (F_ * C_) + i];
  }
  __syncthreads();

  for (int dt = 0; dt < 8; ++dt) {
    int t = t0 + dt;
    const float* pr = dre + (size_t)(b * T_ + t) * (C_ * F_);
    const float* pi_ = dim_ + (size_t)(b * T_ + t) * (C_ * F_);
    for (int f = tid; f < F_; f += 256) {
      float ar = 0.f, ai = 0.f;
#pragma unroll
      for (int c = 0; c < C_; ++c) {
        float xr = pr[c * F_ + f], xi = pi_[c * F_ + f];
        float2 w = wl[c][f];
        ar += w.x * xr + w.y * xi;   // conj(w)*x
        ai += w.x * xi - w.y * xr;
      }
      out[(size_t)(b * T_ + t) * F_ + f] = make_float2(ar, ai);
    }
  }
}

extern "C" void kernel_launch(void* const* d_in, const int* in_sizes, int n_in,
                              void* d_out, int out_size, void* d_ws, size_t ws_size,
                              hipStream_t stream) {
  const float* dre = (const float*)d_in[0];
  const float* dim_ = (const float*)d_in[1];
  const float* ms = (const float*)d_in[2];
  const float* mn = (const float*)d_in[3];
  const float* wmlp = (const float*)d_in[4];
  const float* bmlp = (const float*)d_in[5];
  const float* wgv = (const float*)d_in[6];
  const float* bgv = (const float*)d_in[7];

  char* ws = (char*)d_ws;
  float2* xt    = (float2*)(ws);                    // B*F*C*T float2 = 131,584,000 B
  float2* psd_s = (float2*)(ws + 131584000);        // 1,052,672 B
  float2* psd_n = (float2*)(ws + 132636672);        // 1,052,672 B
  float*  feat  = (float*) (ws + 133689344);        // 65,792 B
  float*  u     = (float*) (ws + 133755136);        // 256 B
  float2* wsv   = (float2*)(ws + 133755392);        // 131,584 B

  dim3 g1(9, 32, B_ * C_), b1(32, 8, 1);
  k_transpose<<<g1, b1, 0, stream>>>(dre, dim_, xt);
  k_psd<<<B_ * F_, 256, 0, stream>>>(xt, ms, mn, psd_s, psd_n, feat);
  k_attn<<<B_, 256, 0, stream>>>(feat, wmlp, bmlp, wgv, bgv, u);
  k_solve<<<B_ * F_, 64, 0, stream>>>(psd_s, psd_n, u, wsv);
  k_bf<<<B_ * 125, 256, 0, stream>>>(dre, dim_, wsv, (float2*)d_out);
}

// Round 2
// 222.989 us; speedup vs baseline: 1.5430x; 1.5430x over previous
//
#include <hip/hip_runtime.h>
#include <math.h>

#define B_ 8
#define T_ 1000
#define C_ 8
#define F_ 257
#define A_ 320

// ---------------- Kernel 1: (B,T,C,F) -> (B,F,C,T) interleaved float2 ----------
__global__ __launch_bounds__(256) void k_transpose(
    const float* __restrict__ dre, const float* __restrict__ dim_,
    float2* __restrict__ xt) {
  __shared__ float2 tile[32][33];
  int bc = blockIdx.z;
  int b = bc >> 3, c = bc & 7;
  int t0 = blockIdx.y * 32, f0 = blockIdx.x * 32;
  int tx = threadIdx.x, ty = threadIdx.y;
#pragma unroll
  for (int j = 0; j < 4; ++j) {
    int t = t0 + ty + j * 8, f = f0 + tx;
    if (t < T_ && f < F_) {
      size_t idx = ((size_t)(b * T_ + t) * C_ + c) * F_ + f;
      tile[ty + j * 8][tx] = make_float2(dre[idx], dim_[idx]);
    }
  }
  __syncthreads();
#pragma unroll
  for (int j = 0; j < 4; ++j) {
    int f = f0 + ty + j * 8, t = t0 + tx;
    if (t < T_ && f < F_) {
      xt[((size_t)(b * F_ + f) * C_ + c) * T_ + t] = tile[tx][ty + j * 8];
    }
  }
}

// ---------------- Kernel 2: PSDs (both masks, one pass) + attention features ----
// t-chunked double-buffered LDS (16 KB total) for occupancy.
#define CH_ 125
__global__ __launch_bounds__(256) void k_psd(
    const float2* __restrict__ xt,
    const float* __restrict__ ms, const float* __restrict__ mn,
    float2* __restrict__ psd_s, float2* __restrict__ psd_n,
    float* __restrict__ feat) {
  __shared__ float2 xl[2][C_][CH_];   // 16000 B
  int bf = blockIdx.x;            // b*F + f
  int b = bf / F_;
  int f = bf - b * F_;
  int tid = threadIdx.x;
  int g = tid >> 5;       // channel c owned by this 32-lane group
  int lane = tid & 31;

  const float2* xg = xt + (size_t)bf * (C_ * T_) + (size_t)g * T_;  // row of channel g
  const float* msg = ms + (size_t)bf * (C_ * T_) + g * T_;
  const float* mng = mn + (size_t)bf * (C_ * T_) + g * T_;

  // stage chunk 0
#pragma unroll
  for (int it = 0; it < 4; ++it) {
    int tt = lane + it * 32;
    if (tt < CH_) xl[0][g][tt] = xg[tt];
  }
  __syncthreads();

  float2 as_[C_], an_[C_];
#pragma unroll
  for (int e = 0; e < C_; ++e) { as_[e] = make_float2(0.f, 0.f); an_[e] = make_float2(0.f, 0.f); }
  float ss = 0.f, sn = 0.f;

  for (int ch = 0; ch < 8; ++ch) {
    int cur = ch & 1;
    if (ch < 7) {                      // prefetch next chunk into other buffer
      int nbase = (ch + 1) * CH_;
#pragma unroll
      for (int it = 0; it < 4; ++it) {
        int tt = lane + it * 32;
        if (tt < CH_) xl[cur ^ 1][g][tt] = xg[nbase + tt];
      }
    }
    int tbase = ch * CH_;
#pragma unroll
    for (int it = 0; it < 4; ++it) {
      int tt = lane + it * 32;
      if (tt < CH_) {
        int t = tbase + tt;
        float vms = msg[t], vmn = mng[t];
        ss += vms; sn += vmn;
        float2 xc = xl[cur][g][tt];
#pragma unroll
        for (int e = 0; e < C_; ++e) {
          float2 xe = xl[cur][e][tt];
          float tre = xc.x * xe.x + xc.y * xe.y;   // xc * conj(xe) .re
          float tim = xc.y * xe.x - xc.x * xe.y;   // .im
          as_[e].x += vms * tre; as_[e].y += vms * tim;
          an_[e].x += vmn * tre; an_[e].y += vmn * tim;
        }
      }
    }
    __syncthreads();
  }

  // reduce across 32 lanes of the group (xor masks < 32 stay in-group)
#pragma unroll
  for (int s = 16; s >= 1; s >>= 1) {
    ss += __shfl_xor(ss, s);
    sn += __shfl_xor(sn, s);
#pragma unroll
    for (int e = 0; e < C_; ++e) {
      as_[e].x += __shfl_xor(as_[e].x, s);
      as_[e].y += __shfl_xor(as_[e].y, s);
      an_[e].x += __shfl_xor(an_[e].x, s);
      an_[e].y += __shfl_xor(an_[e].y, s);
    }
  }

  if (lane == 0) {
    float inv_s = 1.f / (ss + 1e-6f);
    float inv_n = 1.f / (sn + 1e-6f);
    float2* ps = psd_s + (size_t)bf * (C_ * C_) + g * C_;
    float2* pn = psd_n + (size_t)bf * (C_ * C_) + g * C_;
    float sr = 0.f, si = 0.f;
#pragma unroll
    for (int e = 0; e < C_; ++e) {
      float2 vs = make_float2(as_[e].x * inv_s, as_[e].y * inv_s);
      float2 vn = make_float2(an_[e].x * inv_n, an_[e].y * inv_n);
      ps[e] = vs; pn[e] = vn;
      if (e != g) { sr += vs.x; si += vs.y; }
    }
    sr *= (1.f / 7.f); si *= (1.f / 7.f);
    feat[(b * C_ + g) * F_ + f] = sqrtf(sr * sr + si * si);
  }
}

// ---------------- Kernel 3: attention MLP partial logits ----------------------
// grid (B, 5), block 64. Each block: 64 a-rows. b_gvec dropped (softmax-invariant).
__global__ __launch_bounds__(64) void k_attn(
    const float* __restrict__ feat, const float* __restrict__ wmlp,
    const float* __restrict__ bmlp, const float* __restrict__ wgv,
    float* __restrict__ e_part) {
  __shared__ float fl[C_ * F_];   // 8224 B
  int b = blockIdx.x, p = blockIdx.y;
  int tid = threadIdx.x;
  for (int i = tid; i < C_ * F_; i += 64) fl[i] = feat[b * C_ * F_ + i];
  __syncthreads();

  int a = p * 64 + tid;           // A = 320 = 5*64 exactly
  const float* wr = wmlp + a * F_;
  float acc[C_];
  float bm = bmlp[a];
#pragma unroll
  for (int c = 0; c < C_; ++c) acc[c] = bm;
  for (int k = 0; k < F_; ++k) {
    float w = wr[k];
#pragma unroll
    for (int c = 0; c < C_; ++c) acc[c] += w * fl[c * F_ + k];
  }
  float wg = wgv[a];
  float ec[C_];
#pragma unroll
  for (int c = 0; c < C_; ++c) ec[c] = wg * tanhf(acc[c]);

#pragma unroll
  for (int s = 32; s >= 1; s >>= 1) {
#pragma unroll
    for (int c = 0; c < C_; ++c) ec[c] += __shfl_xor(ec[c], s);
  }
  if (tid == 0) {
#pragma unroll
    for (int c = 0; c < C_; ++c) e_part[(b * 5 + p) * C_ + c] = ec[c];
  }
}

// ---------------- Kernel 4: softmax + tik-reg + 8x8 complex solve + ws ---------
__global__ __launch_bounds__(64) void k_solve(
    const float2* __restrict__ psd_s, const float2* __restrict__ psd_n,
    const float* __restrict__ e_part, float2* __restrict__ wsv) {
  int bf = blockIdx.x;
  int b = bf / F_;
  int l = threadIdx.x;
  int r = l >> 3, q = l & 7;

  // softmax over channels (each 8-lane subgroup spans q=0..7)
  float e_c = 0.f;
#pragma unroll
  for (int p = 0; p < 5; ++p) e_c += e_part[(b * 5 + p) * C_ + q];
  e_c *= 2.0f;  // SCALING
  float mx = e_c;
#pragma unroll
  for (int s = 4; s >= 1; s >>= 1) mx = fmaxf(mx, __shfl_xor(mx, s));
  float ex = expf(e_c - mx);
  float sm = ex;
#pragma unroll
  for (int s = 4; s >= 1; s >>= 1) sm += __shfl_xor(sm, s);
  float uq = ex / sm;

  float2 M = psd_n[(size_t)bf * 64 + l];
  float2 R = psd_s[(size_t)bf * 64 + l];

  // trace(psd_n).real
  float td = (r == q) ? M.x : 0.f;
#pragma unroll
  for (int s = 32; s >= 1; s >>= 1) td += __shfl_xor(td, s);
  if (r == q) M.x += 1e-7f * (td * 0.125f) + 1e-8f;

  // Gauss-Jordan: M X = R  ->  R becomes X
#pragma unroll
  for (int k = 0; k < 8; ++k) {
    float pr = __shfl(M.x, k * 9), pi = __shfl(M.y, k * 9);
    float den = pr * pr + pi * pi;
    float ir = pr / den, ii = -pi / den;          // 1/pivot
    float mkr = __shfl(M.x, k * 8 + q), mki = __shfl(M.y, k * 8 + q);
    float rkr = __shfl(R.x, k * 8 + q), rki = __shfl(R.y, k * 8 + q);
    float gr = __shfl(M.x, r * 8 + k), gi = __shfl(M.y, r * 8 + k);
    if (r == k) {
      float nmr = M.x * ir - M.y * ii, nmi = M.x * ii + M.y * ir;
      float nrr = R.x * ir - R.y * ii, nri = R.x * ii + R.y * ir;
      M = make_float2(nmr, nmi); R = make_float2(nrr, nri);
    } else {
      float fr = gr * ir - gi * ii, fi = gr * ii + gi * ir;   // M[r,k]/pivot
      M.x -= fr * mkr - fi * mki; M.y -= fr * mki + fi * mkr;
      R.x -= fr * rkr - fi * rki; R.y -= fr * rki + fi * rkr;
    }
  }

  // trace(X), normalize, apply u
  float trr = (r == q) ? R.x : 0.f, tri = (r == q) ? R.y : 0.f;
#pragma unroll
  for (int s = 32; s >= 1; s >>= 1) { trr += __shfl_xor(trr, s); tri += __shfl_xor(tri, s); }
  trr += 1e-6f;  // + EPS (real)
  float den = trr * trr + tri * tri;
  float ir = trr / den, ii = -tri / den;
  float wr_ = R.x * ir - R.y * ii;   // ws_mat[r][q]
  float wi_ = R.x * ii + R.y * ir;
  float vr = wr_ * uq, vi = wi_ * uq;
#pragma unroll
  for (int s = 4; s >= 1; s >>= 1) { vr += __shfl_xor(vr, s); vi += __shfl_xor(vi, s); }
  if (q == 0) wsv[(size_t)bf * C_ + r] = make_float2(vr, vi);
}

// ---------------- Kernel 5: enhanced[b,t,f] = sum_c conj(ws) * x ----------------
__global__ __launch_bounds__(256) void k_bf(
    const float* __restrict__ dre, const float* __restrict__ dim_,
    const float2* __restrict__ wsv, float2* __restrict__ out) {
  __shared__ float2 wl[C_][F_];
  int blk = blockIdx.x;
  int b = blk / 125;
  int t0 = (blk - b * 125) * 8;
  int tid = threadIdx.x;
  // wsv layout [b][f][c] -> wl[c][f]
  for (int i = tid; i < C_ * F_; i += 256) {
    int f = i >> 3, c = i & 7;
    wl[c][f] = wsv[(size_t)b * (F_ * C_) + i];
  }
  __syncthreads();

  for (int dt = 0; dt < 8; ++dt) {
    int t = t0 + dt;
    const float* pr = dre + (size_t)(b * T_ + t) * (C_ * F_);
    const float* pi_ = dim_ + (size_t)(b * T_ + t) * (C_ * F_);
    for (int f = tid; f < F_; f += 256) {
      float ar = 0.f, ai = 0.f;
#pragma unroll
      for (int c = 0; c < C_; ++c) {
        float xr = pr[c * F_ + f], xi = pi_[c * F_ + f];
        float2 w = wl[c][f];
        ar += w.x * xr + w.y * xi;   // conj(w)*x
        ai += w.x * xi - w.y * xr;
      }
      out[(size_t)(b * T_ + t) * F_ + f] = make_float2(ar, ai);
    }
  }
}

extern "C" void kernel_launch(void* const* d_in, const int* in_sizes, int n_in,
                              void* d_out, int out_size, void* d_ws, size_t ws_size,
                              hipStream_t stream) {
  const float* dre = (const float*)d_in[0];
  const float* dim_ = (const float*)d_in[1];
  const float* ms = (const float*)d_in[2];
  const float* mn = (const float*)d_in[3];
  const float* wmlp = (const float*)d_in[4];
  const float* bmlp = (const float*)d_in[5];
  const float* wgv = (const float*)d_in[6];
  // d_in[7] = b_gvec: constant shift, cancels in softmax — unused.

  char* ws = (char*)d_ws;
  float2* xt    = (float2*)(ws);                    // B*F*C*T float2 = 131,584,000 B
  float2* psd_s = (float2*)(ws + 131584000);        // 1,052,672 B
  float2* psd_n = (float2*)(ws + 132636672);        // 1,052,672 B
  float*  feat  = (float*) (ws + 133689344);        // 65,792 B
  float*  e_prt = (float*) (ws + 133755136);        // 8*5*8*4 = 1,280 B
  float2* wsv   = (float2*)(ws + 133756416);        // 131,584 B

  dim3 g1(9, 32, B_ * C_), b1(32, 8, 1);
  k_transpose<<<g1, b1, 0, stream>>>(dre, dim_, xt);
  k_psd<<<B_ * F_, 256, 0, stream>>>(xt, ms, mn, psd_s, psd_n, feat);
  dim3 ga(B_, 5, 1);
  k_attn<<<ga, 64, 0, stream>>>(feat, wmlp, bmlp, wgv, e_prt);
  k_solve<<<B_ * F_, 64, 0, stream>>>(psd_s, psd_n, e_prt, wsv);
  k_bf<<<B_ * 125, 256, 0, stream>>>(dre, dim_, wsv, (float2*)d_out);
}

// Round 3
// 203.917 us; speedup vs baseline: 1.6873x; 1.0935x over previous
//
#include <hip/hip_runtime.h>
#include <math.h>

#define B_ 8
#define T_ 1000
#define C_ 8
#define F_ 257
#define A_ 320

// ---------------- Kernel 1: (B,T,C,F) -> (B,F,C,T) interleaved float2 ----------
__global__ __launch_bounds__(256) void k_transpose(
    const float* __restrict__ dre, const float* __restrict__ dim_,
    float2* __restrict__ xt) {
  __shared__ float2 tile[32][33];
  int bc = blockIdx.z;
  int b = bc >> 3, c = bc & 7;
  int t0 = blockIdx.y * 32, f0 = blockIdx.x * 32;
  int tx = threadIdx.x, ty = threadIdx.y;
#pragma unroll
  for (int j = 0; j < 4; ++j) {
    int t = t0 + ty + j * 8, f = f0 + tx;
    if (t < T_ && f < F_) {
      size_t idx = ((size_t)(b * T_ + t) * C_ + c) * F_ + f;
      tile[ty + j * 8][tx] = make_float2(dre[idx], dim_[idx]);
    }
  }
  __syncthreads();
#pragma unroll
  for (int j = 0; j < 4; ++j) {
    int f = f0 + ty + j * 8, t = t0 + tx;
    if (t < T_ && f < F_) {
      xt[((size_t)(b * F_ + f) * C_ + c) * T_ + t] = tile[tx][ty + j * 8];
    }
  }
}

// ---------------- Kernel 2: PSDs (both masks, one pass) + attention features ----
// t-chunked double-buffered LDS; T14 async-STAGE: next chunk's x AND masks are
// loaded into registers BEFORE compute, ds_write after compute, so HBM/L3
// latency hides under the chunk's FMA work.
#define CH_ 125
__global__ __launch_bounds__(256) void k_psd(
    const float2* __restrict__ xt,
    const float* __restrict__ ms, const float* __restrict__ mn,
    float2* __restrict__ psd_s, float2* __restrict__ psd_n,
    float* __restrict__ feat) {
  __shared__ float2 xl[2][C_][CH_];   // 16000 B
  int bf = blockIdx.x;            // b*F + f
  int b = bf / F_;
  int f = bf - b * F_;
  int tid = threadIdx.x;
  int g = tid >> 5;       // channel c owned by this 32-lane group
  int lane = tid & 31;

  const float2* xg = xt + (size_t)bf * (C_ * T_) + (size_t)g * T_;  // row of channel g
  const float* msg = ms + (size_t)bf * (C_ * T_) + g * T_;
  const float* mng = mn + (size_t)bf * (C_ * T_) + g * T_;

  float2 xnx[4];            // staged x for next chunk
  float msx[4], mnx[4];     // staged masks for next chunk
  float ms4[4], mn4[4];     // masks for current chunk (registers)

  // prologue: chunk 0 -> regs -> LDS
#pragma unroll
  for (int it = 0; it < 4; ++it) {
    int tt = lane + it * 32;
    bool ok = tt < CH_;
    xnx[it] = ok ? xg[tt] : make_float2(0.f, 0.f);
    ms4[it] = ok ? msg[tt] : 0.f;
    mn4[it] = ok ? mng[tt] : 0.f;
  }
#pragma unroll
  for (int it = 0; it < 4; ++it) {
    int tt = lane + it * 32;
    if (tt < CH_) xl[0][g][tt] = xnx[it];
  }
  __syncthreads();

  float2 as_[C_], an_[C_];
#pragma unroll
  for (int e = 0; e < C_; ++e) { as_[e] = make_float2(0.f, 0.f); an_[e] = make_float2(0.f, 0.f); }
  float ss = 0.f, sn = 0.f;

  for (int ch = 0; ch < 8; ++ch) {
    int cur = ch & 1;
    // (1) issue next chunk's loads into registers (latency hides under compute)
    if (ch < 7) {
      int nbase = (ch + 1) * CH_;
#pragma unroll
      for (int it = 0; it < 4; ++it) {
        int tt = lane + it * 32;
        bool ok = tt < CH_;
        xnx[it] = ok ? xg[nbase + tt] : make_float2(0.f, 0.f);
        msx[it] = ok ? msg[nbase + tt] : 0.f;
        mnx[it] = ok ? mng[nbase + tt] : 0.f;
      }
    }
    // (2) compute current chunk from LDS + mask registers
#pragma unroll
    for (int it = 0; it < 4; ++it) {
      int tt = lane + it * 32;
      if (tt < CH_) {
        float vms = ms4[it], vmn = mn4[it];
        ss += vms; sn += vmn;
        float2 xc = xl[cur][g][tt];
#pragma unroll
        for (int e = 0; e < C_; ++e) {
          float2 xe = xl[cur][e][tt];
          float tre = xc.x * xe.x + xc.y * xe.y;   // xc * conj(xe) .re
          float tim = xc.y * xe.x - xc.x * xe.y;   // .im
          as_[e].x += vms * tre; as_[e].y += vms * tim;
          an_[e].x += vmn * tre; an_[e].y += vmn * tim;
        }
      }
    }
    // (3) write staged x to the other LDS buffer, roll mask regs
    if (ch < 7) {
#pragma unroll
      for (int it = 0; it < 4; ++it) {
        int tt = lane + it * 32;
        if (tt < CH_) xl[cur ^ 1][g][tt] = xnx[it];
      }
#pragma unroll
      for (int it = 0; it < 4; ++it) { ms4[it] = msx[it]; mn4[it] = mnx[it]; }
    }
    // (4) one barrier per chunk
    __syncthreads();
  }

  // reduce across 32 lanes of the group (xor masks < 32 stay in-group)
#pragma unroll
  for (int s = 16; s >= 1; s >>= 1) {
    ss += __shfl_xor(ss, s);
    sn += __shfl_xor(sn, s);
#pragma unroll
    for (int e = 0; e < C_; ++e) {
      as_[e].x += __shfl_xor(as_[e].x, s);
      as_[e].y += __shfl_xor(as_[e].y, s);
      an_[e].x += __shfl_xor(an_[e].x, s);
      an_[e].y += __shfl_xor(an_[e].y, s);
    }
  }

  if (lane == 0) {
    float inv_s = 1.f / (ss + 1e-6f);
    float inv_n = 1.f / (sn + 1e-6f);
    float2* ps = psd_s + (size_t)bf * (C_ * C_) + g * C_;
    float2* pn = psd_n + (size_t)bf * (C_ * C_) + g * C_;
    float sr = 0.f, si = 0.f;
#pragma unroll
    for (int e = 0; e < C_; ++e) {
      float2 vs = make_float2(as_[e].x * inv_s, as_[e].y * inv_s);
      float2 vn = make_float2(an_[e].x * inv_n, an_[e].y * inv_n);
      ps[e] = vs; pn[e] = vn;
      if (e != g) { sr += vs.x; si += vs.y; }
    }
    sr *= (1.f / 7.f); si *= (1.f / 7.f);
    feat[(b * C_ + g) * F_ + f] = sqrtf(sr * sr + si * si);
  }
}

// ---------------- Kernel 3: attention MLP partial logits ----------------------
// grid (B, 5), block 64. Each block: 64 a-rows. b_gvec dropped (softmax-invariant).
__global__ __launch_bounds__(64) void k_attn(
    const float* __restrict__ feat, const float* __restrict__ wmlp,
    const float* __restrict__ bmlp, const float* __restrict__ wgv,
    float* __restrict__ e_part) {
  __shared__ float fl[C_ * F_];   // 8224 B
  int b = blockIdx.x, p = blockIdx.y;
  int tid = threadIdx.x;
  for (int i = tid; i < C_ * F_; i += 64) fl[i] = feat[b * C_ * F_ + i];
  __syncthreads();

  int a = p * 64 + tid;           // A = 320 = 5*64 exactly
  const float* wr = wmlp + a * F_;
  float acc[C_];
  float bm = bmlp[a];
#pragma unroll
  for (int c = 0; c < C_; ++c) acc[c] = bm;
  for (int k = 0; k < F_; ++k) {
    float w = wr[k];
#pragma unroll
    for (int c = 0; c < C_; ++c) acc[c] += w * fl[c * F_ + k];
  }
  float wg = wgv[a];
  float ec[C_];
#pragma unroll
  for (int c = 0; c < C_; ++c) ec[c] = wg * tanhf(acc[c]);

#pragma unroll
  for (int s = 32; s >= 1; s >>= 1) {
#pragma unroll
    for (int c = 0; c < C_; ++c) ec[c] += __shfl_xor(ec[c], s);
  }
  if (tid == 0) {
#pragma unroll
    for (int c = 0; c < C_; ++c) e_part[(b * 5 + p) * C_ + c] = ec[c];
  }
}

// ---------------- Kernel 4: softmax + tik-reg + 8x8 complex solve + ws ---------
__global__ __launch_bounds__(64) void k_solve(
    const float2* __restrict__ psd_s, const float2* __restrict__ psd_n,
    const float* __restrict__ e_part, float2* __restrict__ wsv) {
  int bf = blockIdx.x;
  int b = bf / F_;
  int l = threadIdx.x;
  int r = l >> 3, q = l & 7;

  // softmax over channels (each 8-lane subgroup spans q=0..7)
  float e_c = 0.f;
#pragma unroll
  for (int p = 0; p < 5; ++p) e_c += e_part[(b * 5 + p) * C_ + q];
  e_c *= 2.0f;  // SCALING
  float mx = e_c;
#pragma unroll
  for (int s = 4; s >= 1; s >>= 1) mx = fmaxf(mx, __shfl_xor(mx, s));
  float ex = expf(e_c - mx);
  float sm = ex;
#pragma unroll
  for (int s = 4; s >= 1; s >>= 1) sm += __shfl_xor(sm, s);
  float uq = ex / sm;

  float2 M = psd_n[(size_t)bf * 64 + l];
  float2 R = psd_s[(size_t)bf * 64 + l];

  // trace(psd_n).real
  float td = (r == q) ? M.x : 0.f;
#pragma unroll
  for (int s = 32; s >= 1; s >>= 1) td += __shfl_xor(td, s);
  if (r == q) M.x += 1e-7f * (td * 0.125f) + 1e-8f;

  // Gauss-Jordan: M X = R  ->  R becomes X
#pragma unroll
  for (int k = 0; k < 8; ++k) {
    float pr = __shfl(M.x, k * 9), pi = __shfl(M.y, k * 9);
    float den = pr * pr + pi * pi;
    float ir = pr / den, ii = -pi / den;          // 1/pivot
    float mkr = __shfl(M.x, k * 8 + q), mki = __shfl(M.y, k * 8 + q);
    float rkr = __shfl(R.x, k * 8 + q), rki = __shfl(R.y, k * 8 + q);
    float gr = __shfl(M.x, r * 8 + k), gi = __shfl(M.y, r * 8 + k);
    if (r == k) {
      float nmr = M.x * ir - M.y * ii, nmi = M.x * ii + M.y * ir;
      float nrr = R.x * ir - R.y * ii, nri = R.x * ii + R.y * ir;
      M = make_float2(nmr, nmi); R = make_float2(nrr, nri);
    } else {
      float fr = gr * ir - gi * ii, fi = gr * ii + gi * ir;   // M[r,k]/pivot
      M.x -= fr * mkr - fi * mki; M.y -= fr * mki + fi * mkr;
      R.x -= fr * rkr - fi * rki; R.y -= fr * rki + fi * rkr;
    }
  }

  // trace(X), normalize, apply u
  float trr = (r == q) ? R.x : 0.f, tri = (r == q) ? R.y : 0.f;
#pragma unroll
  for (int s = 32; s >= 1; s >>= 1) { trr += __shfl_xor(trr, s); tri += __shfl_xor(tri, s); }
  trr += 1e-6f;  // + EPS (real)
  float den = trr * trr + tri * tri;
  float ir = trr / den, ii = -tri / den;
  float wr_ = R.x * ir - R.y * ii;   // ws_mat[r][q]
  float wi_ = R.x * ii + R.y * ir;
  float vr = wr_ * uq, vi = wi_ * uq;
#pragma unroll
  for (int s = 4; s >= 1; s >>= 1) { vr += __shfl_xor(vr, s); vi += __shfl_xor(vi, s); }
  if (q == 0) wsv[(size_t)bf * C_ + r] = make_float2(vr, vi);
}

// ---------------- Kernel 5: enhanced[b,t,f] = sum_c conj(ws) * x ----------------
__global__ __launch_bounds__(256) void k_bf(
    const float* __restrict__ dre, const float* __restrict__ dim_,
    const float2* __restrict__ wsv, float2* __restrict__ out) {
  __shared__ float2 wl[C_][F_];
  int blk = blockIdx.x;
  int b = blk / 125;
  int t0 = (blk - b * 125) * 8;
  int tid = threadIdx.x;
  // wsv layout [b][f][c] -> wl[c][f]
  for (int i = tid; i < C_ * F_; i += 256) {
    int f = i >> 3, c = i & 7;
    wl[c][f] = wsv[(size_t)b * (F_ * C_) + i];
  }
  __syncthreads();

  for (int dt = 0; dt < 8; ++dt) {
    int t = t0 + dt;
    const float* pr = dre + (size_t)(b * T_ + t) * (C_ * F_);
    const float* pi_ = dim_ + (size_t)(b * T_ + t) * (C_ * F_);
    for (int f = tid; f < F_; f += 256) {
      float ar = 0.f, ai = 0.f;
#pragma unroll
      for (int c = 0; c < C_; ++c) {
        float xr = pr[c * F_ + f], xi = pi_[c * F_ + f];
        float2 w = wl[c][f];
        ar += w.x * xr + w.y * xi;   // conj(w)*x
        ai += w.x * xi - w.y * xr;
      }
      out[(size_t)(b * T_ + t) * F_ + f] = make_float2(ar, ai);
    }
  }
}

extern "C" void kernel_launch(void* const* d_in, const int* in_sizes, int n_in,
                              void* d_out, int out_size, void* d_ws, size_t ws_size,
                              hipStream_t stream) {
  const float* dre = (const float*)d_in[0];
  const float* dim_ = (const float*)d_in[1];
  const float* ms = (const float*)d_in[2];
  const float* mn = (const float*)d_in[3];
  const float* wmlp = (const float*)d_in[4];
  const float* bmlp = (const float*)d_in[5];
  const float* wgv = (const float*)d_in[6];
  // d_in[7] = b_gvec: constant shift, cancels in softmax — unused.

  char* ws = (char*)d_ws;
  float2* xt    = (float2*)(ws);                    // B*F*C*T float2 = 131,584,000 B
  float2* psd_s = (float2*)(ws + 131584000);        // 1,052,672 B
  float2* psd_n = (float2*)(ws + 132636672);        // 1,052,672 B
  float*  feat  = (float*) (ws + 133689344);        // 65,792 B
  float*  e_prt = (float*) (ws + 133755136);        // 8*5*8*4 = 1,280 B
  float2* wsv   = (float2*)(ws + 133756416);        // 131,584 B

  dim3 g1(9, 32, B_ * C_), b1(32, 8, 1);
  k_transpose<<<g1, b1, 0, stream>>>(dre, dim_, xt);
  k_psd<<<B_ * F_, 256, 0, stream>>>(xt, ms, mn, psd_s, psd_n, feat);
  dim3 ga(B_, 5, 1);
  k_attn<<<ga, 64, 0, stream>>>(feat, wmlp, bmlp, wgv, e_prt);
  k_solve<<<B_ * F_, 64, 0, stream>>>(psd_s, psd_n, e_prt, wsv);
  k_bf<<<B_ * 125, 256, 0, stream>>>(dre, dim_, wsv, (float2*)d_out);
}